// Round 4
// baseline (687.406 us; speedup 1.0000x reference)
//
#include <hip/hip_runtime.h>
#include <math.h>

typedef unsigned int   u32;
typedef unsigned short u16;
typedef short short8 __attribute__((ext_vector_type(8)));   // 8 bf16 = 4 VGPRs
typedef float f32x4   __attribute__((ext_vector_type(4)));
typedef float f32x16  __attribute__((ext_vector_type(16)));

constexpr int B    = 2048;
constexpr int D    = 512;
constexpr int N    = 100000;
constexpr int KTOP = 5;
constexpr int NK   = 16;                  // 512 / 32 (fallback path)

// Big path: 32x32x16 MFMA. 32-point groups (pg32) are the N-tile unit.
constexpr int NPART    = 48;
constexpr int CHUNK    = 2112;            // 66 pg32 of 32; 48*2112 = 101376 >= N
constexpr int ITERS    = CHUNK / 32;      // 66
constexpr int NPTS_PAD = NPART * CHUNK;   // 101376
constexpr int NPG32    = NPTS_PAD / 32;   // 3168

__device__ __forceinline__ u16 f2bf(float f) {   // RNE, finite normals
    u32 u = __float_as_uint(f);
    return (u16)((u + 0x7fffu + ((u >> 16) & 1u)) >> 16);
}

__device__ __forceinline__ void gld_lds16(const void* g, void* l) {
    __builtin_amdgcn_global_load_lds((const __attribute__((address_space(1))) u32*)g,
                                     (__attribute__((address_space(3))) u32*)l, 16, 0, 0);
}

__device__ __forceinline__ void ins5(float (&s)[KTOP], int (&x)[KTOP], float v, int p) {
    if (v > s[KTOP - 1]) {                 // strict >: earlier (lower) idx wins ties
        s[KTOP - 1] = v; x[KTOP - 1] = p;
#pragma unroll
        for (int k = KTOP - 1; k > 0; --k) {
            if (s[k] > s[k - 1]) {
                float tf = s[k]; s[k] = s[k - 1]; s[k - 1] = tf;
                int   tg = x[k]; x[k] = x[k - 1]; x[k - 1] = tg;
            }
        }
    }
}

__device__ __forceinline__ void merge_xor(float (&s)[KTOP], int (&x)[KTOP], int mask) {
    float bs[KTOP], as[KTOP]; int bx[KTOP], ax[KTOP];
#pragma unroll
    for (int k = 0; k < KTOP; ++k) {
        bs[k] = __shfl_xor(s[k], mask); bx[k] = __shfl_xor(x[k], mask);
        as[k] = s[k]; ax[k] = x[k];
    }
#pragma unroll
    for (int k = 0; k < KTOP; ++k) {
        bool ta = (as[0] > bs[0]) || ((as[0] == bs[0]) && (ax[0] < bx[0]));
        s[k] = ta ? as[0] : bs[0];
        x[k] = ta ? ax[0] : bx[0];
#pragma unroll
        for (int m = 0; m < KTOP - 1; ++m) {
            as[m] = ta ? as[m + 1] : as[m];     ax[m] = ta ? ax[m + 1] : ax[m];
            bs[m] = ta ? bs[m]     : bs[m + 1]; bx[m] = ta ? bx[m]     : bx[m + 1];
        }
        as[KTOP - 1] = ta ? -INFINITY : as[KTOP - 1];
        bs[KTOP - 1] = ta ? bs[KTOP - 1] : -INFINITY;
    }
}

// ---- Q -> bf16 B-frags for 32x32x16: lane = (q&31) + 32*octet, k contiguous 8
__global__ void prep_q32(const float* __restrict__ Q, u16* __restrict__ Qbf) {
    int tid  = blockIdx.x * 256 + threadIdx.x;     // 131072 = 2048*64
    int q    = tid >> 6;
    int koct = tid & 63;                           // k = koct*8 .. +7
    const float4* src = (const float4*)(Q + (size_t)q * D + koct * 8);
    float4 a = src[0], b = src[1];
    u32 p0 = (u32)f2bf(a.x) | ((u32)f2bf(a.y) << 16);
    u32 p1 = (u32)f2bf(a.z) | ((u32)f2bf(a.w) << 16);
    u32 p2 = (u32)f2bf(b.x) | ((u32)f2bf(b.y) << 16);
    u32 p3 = (u32)f2bf(b.z) | ((u32)f2bf(b.w) << 16);
    int kstep = koct >> 1, octet = koct & 1;
    int lane  = (q & 31) + 32 * octet;
    size_t frag = (size_t)(q >> 5) * 32 + kstep;
    *(uint4*)(Qbf + (frag * 64 + lane) * 8) = make_uint4(p0, p1, p2, p3);
}

// ---- Q -> bf16 in 16x16x32 B-frag order (fallback path) -------------------
__global__ void prep_q16(const float* __restrict__ Q, u16* __restrict__ Qbf) {
    int tid  = blockIdx.x * 256 + threadIdx.x;     // 131072
    int q    = tid >> 6;
    int koct = tid & 63;
    const float4* src = (const float4*)(Q + (size_t)q * D + koct * 8);
    float4 a = src[0], b = src[1];
    u32 p0 = (u32)f2bf(a.x) | ((u32)f2bf(a.y) << 16);
    u32 p1 = (u32)f2bf(a.z) | ((u32)f2bf(a.w) << 16);
    u32 p2 = (u32)f2bf(b.x) | ((u32)f2bf(b.y) << 16);
    u32 p3 = (u32)f2bf(b.z) | ((u32)f2bf(b.w) << 16);
    int frag = (q >> 4) * NK + (koct >> 2);
    int lane = (q & 15) + 16 * (koct & 3);
    *(uint4*)(Qbf + (size_t)frag * 512 + lane * 8) = make_uint4(p0, p1, p2, p3);
}

// ---- X -> bf16 A-frags for 32x32x16 (lane = point&31 + 32*octet) + fused x2
__global__ void prep_x2(const float* __restrict__ X, u16* __restrict__ Xbf,
                        float* __restrict__ x2) {
    __shared__ float psum[4][32];
    const int t = threadIdx.x, lane = t & 63, wave = t >> 6;
    const int pg    = blockIdx.x;                 // 0..NPG32-1
    const int pt    = lane & 31, octet = lane >> 5;
    const int point = pg * 32 + pt;
    float ssum = 0.f;
#pragma unroll
    for (int u = 0; u < 8; ++u) {
        int kstep = wave * 8 + u;                 // 0..31
        int k     = kstep * 16 + octet * 8;
        uint4 o = make_uint4(0u, 0u, 0u, 0u);
        if (point < N) {
            const float4* src = (const float4*)(X + (size_t)point * D + k);
            float4 a = src[0], b = src[1];
            ssum = fmaf(a.x, a.x, ssum); ssum = fmaf(a.y, a.y, ssum);
            ssum = fmaf(a.z, a.z, ssum); ssum = fmaf(a.w, a.w, ssum);
            ssum = fmaf(b.x, b.x, ssum); ssum = fmaf(b.y, b.y, ssum);
            ssum = fmaf(b.z, b.z, ssum); ssum = fmaf(b.w, b.w, ssum);
            o.x = (u32)f2bf(a.x) | ((u32)f2bf(a.y) << 16);
            o.y = (u32)f2bf(a.z) | ((u32)f2bf(a.w) << 16);
            o.z = (u32)f2bf(b.x) | ((u32)f2bf(b.y) << 16);
            o.w = (u32)f2bf(b.z) | ((u32)f2bf(b.w) << 16);
        }
        *(uint4*)(Xbf + (((size_t)pg * 32 + kstep) * 64 + lane) * 8) = o;
    }
    ssum += __shfl_xor(ssum, 32);                 // combine the two k-octets
    if (octet == 0) psum[wave][pt] = ssum;
    __syncthreads();
    if (t < 32) {
        float s = psum[0][t] + psum[1][t] + psum[2][t] + psum[3][t];
        x2[pg * 32 + t] = (pg * 32 + t < N) ? s : INFINITY;
    }
}

// ---- x2 (fallback path only) ----------------------------------------------
__global__ void x2_kernel(const float* __restrict__ X, float* __restrict__ x2, int total) {
    int lane = threadIdx.x & 63;
    int wid  = (int)((blockIdx.x * blockDim.x + threadIdx.x) >> 6);
    if (wid >= total) return;
    if (wid >= N) { if (lane == 0) x2[wid] = INFINITY; return; }
    const float* row = X + (size_t)wid * D;
    float s = 0.f;
    for (int c = lane; c < D; c += 64) { float v = row[c]; s = fmaf(v, v, s); }
#pragma unroll
    for (int off = 32; off > 0; off >>= 1) s += __shfl_down(s, off);
    if (lane == 0) x2[wid] = s;
}

// ---- main: 32x32x16 MFMA, 32 resident queries/wave (bq = 128 VGPRs), one
// f32x16 accumulator. FLOP per LDS-A-byte doubles vs 16x16x32 (round-3 was
// LDS-bound at ~55 TB/s). 2 half-buffers of 16 ksteps (16KB each); 2 barriers
// per 32 MFMAs. Grid 48x16 = 768 blocks = exactly 3/CU (launch_bounds 256,3).
__launch_bounds__(256, 3)
__global__ void knn_qreg(const u16* __restrict__ Xbf, const u16* __restrict__ Qbf,
                         const float* __restrict__ x2g,
                         float* __restrict__ cand_s, int* __restrict__ cand_i) {
    __shared__ __attribute__((aligned(16))) u16 Afr[2][16 * 512];   // 2 x 16KB
    const int t    = threadIdx.x;
    const int lane = t & 63;
    const int wave = t >> 6;              // 0..3
    const int hid  = lane >> 5;           // k-octet / C-row +4 selector
    const int col  = lane & 31;           // query within group
    const int part = blockIdx.x;          // 0..47  (48 == 0 mod 8: all 16 qb of
    const int qb   = blockIdx.y;          // 0..15   a part land on one XCD)
    const int pg0    = part * ITERS;
    const int pstart = part * CHUNK;

    // Resident Q: 32 queries x 32 ksteps; B-frag lane holds col, k-octet hid
    const int qg = qb * 4 + wave;         // 0..63
    short8 bq[32];
#pragma unroll
    for (int ks = 0; ks < 32; ++ks)
        bq[ks] = *(const short8*)(Qbf + (((size_t)qg * 32 + ks) * 64 + lane) * 8);
    // Pin bq in registers: memory clobber forbids re-loading from Qbf in-loop.
    asm volatile("" ::: "memory");

    float ss[KTOP]; int si[KTOP];
#pragma unroll
    for (int k = 0; k < KTOP; ++k) { ss[k] = -INFINITY; si[k] = 0x7fffffff; }

    // Stage half h (16 ksteps = 16KB) of pg32 (pg0+it); wave w stages ksteps
    // h*16 + w*4 .. +3. LDS dst is wave-uniform base + lane*16 (gld_lds req).
    auto issue = [&](int it, int h) {
        const size_t fb = ((size_t)(pg0 + it) * 32 + h * 16 + wave * 4) * 64;
        const u16* src = Xbf + (fb + lane) * 8;
        u16* dst = Afr[h] + ((wave * 4) * 64 + lane) * 8;
#pragma unroll
        for (int f = 0; f < 4; ++f)
            gld_lds16(src + (size_t)f * 512, dst + f * 512);
    };

    issue(0, 0);
    for (int it = 0; it < ITERS; ++it) {
        __syncthreads();                   // drains Afr[0] staging; all waves done with Afr[1]
        issue(it, 1);
        f32x16 acc = (f32x16)0.f;
#pragma unroll
        for (int k = 0; k < 16; ++k) {
            short8 af = *(const short8*)&Afr[0][k * 512 + lane * 8];
            acc = __builtin_amdgcn_mfma_f32_32x32x16_bf16(af, bq[k], acc, 0, 0, 0);
        }
        __syncthreads();                   // drains Afr[1] staging; all waves done with Afr[0]
        if (it + 1 < ITERS) issue(it + 1, 0);
#pragma unroll
        for (int k = 0; k < 16; ++k) {
            short8 af = *(const short8*)&Afr[1][k * 512 + lane * 8];
            acc = __builtin_amdgcn_mfma_f32_32x32x16_bf16(af, bq[16 + k], acc, 0, 0, 0);
        }
        // C layout: col=lane&31 (query), row=(reg&3)+8*(reg>>2)+4*hid (point)
        const int PA = pstart + it * 32 + hid * 4;
        float4 xx0 = *(const float4*)(x2g + PA);
        float4 xx1 = *(const float4*)(x2g + PA + 8);
        float4 xx2 = *(const float4*)(x2g + PA + 16);
        float4 xx3 = *(const float4*)(x2g + PA + 24);
        float s0  = fmaf(2.f, acc[0],  -xx0.x), s1  = fmaf(2.f, acc[1],  -xx0.y);
        float s2  = fmaf(2.f, acc[2],  -xx0.z), s3  = fmaf(2.f, acc[3],  -xx0.w);
        float s4  = fmaf(2.f, acc[4],  -xx1.x), s5  = fmaf(2.f, acc[5],  -xx1.y);
        float s6  = fmaf(2.f, acc[6],  -xx1.z), s7  = fmaf(2.f, acc[7],  -xx1.w);
        float s8  = fmaf(2.f, acc[8],  -xx2.x), s9  = fmaf(2.f, acc[9],  -xx2.y);
        float s10 = fmaf(2.f, acc[10], -xx2.z), s11 = fmaf(2.f, acc[11], -xx2.w);
        float s12 = fmaf(2.f, acc[12], -xx3.x), s13 = fmaf(2.f, acc[13], -xx3.y);
        float s14 = fmaf(2.f, acc[14], -xx3.z), s15 = fmaf(2.f, acc[15], -xx3.w);
        float m0 = fmaxf(fmaxf(s0, s1),   fmaxf(s2, s3));
        float m1 = fmaxf(fmaxf(s4, s5),   fmaxf(s6, s7));
        float m2 = fmaxf(fmaxf(s8, s9),   fmaxf(s10, s11));
        float m3 = fmaxf(fmaxf(s12, s13), fmaxf(s14, s15));
        float mx = fmaxf(fmaxf(m0, m1), fmaxf(m2, m3));
        if (mx > ss[KTOP - 1]) {
            ins5(ss, si, s0,  PA + 0);  ins5(ss, si, s1,  PA + 1);
            ins5(ss, si, s2,  PA + 2);  ins5(ss, si, s3,  PA + 3);
            ins5(ss, si, s4,  PA + 8);  ins5(ss, si, s5,  PA + 9);
            ins5(ss, si, s6,  PA + 10); ins5(ss, si, s7,  PA + 11);
            ins5(ss, si, s8,  PA + 16); ins5(ss, si, s9,  PA + 17);
            ins5(ss, si, s10, PA + 18); ins5(ss, si, s11, PA + 19);
            ins5(ss, si, s12, PA + 24); ins5(ss, si, s13, PA + 25);
            ins5(ss, si, s14, PA + 26); ins5(ss, si, s15, PA + 27);
        }
    }

    merge_xor(ss, si, 32);                // lanes l, l^32 hold the same query
    if (hid == 0) {
        int q = qg * 32 + col;
        size_t base = ((size_t)q * NPART + part) * KTOP;
#pragma unroll
        for (int k = 0; k < KTOP; ++k) { cand_s[base + k] = ss[k]; cand_i[base + k] = si[k]; }
    }
}

// ---- fallback main (round-2/3 proven path, in-loop conversion) ------------
__launch_bounds__(256)
__global__ void knn_conv(const float* __restrict__ X, const u16* __restrict__ Qbf,
                         const float* __restrict__ x2g,
                         float* __restrict__ cand_s, int* __restrict__ cand_i) {
    __shared__ __attribute__((aligned(16))) u16 Bfr[16 * 512];
    __shared__ __attribute__((aligned(16))) u16 Afr[4 * 512];
    __shared__ float x2s[64];
    const int t = threadIdx.x, lane = t & 63, wave = t >> 6;
    const int quad = lane >> 4, col = lane & 15;
    const int qb = blockIdx.x, part = blockIdx.y;
    const int pstart = part * 782;
    const int pend   = min(pstart + 782, N);

    float ss[4][KTOP]; int si[4][KTOP];
#pragma unroll
    for (int j = 0; j < 4; ++j)
#pragma unroll
        for (int k = 0; k < KTOP; ++k) { ss[j][k] = -INFINITY; si[j][k] = 0x7fffffff; }

    const int nsub = (pend - pstart + 63) / 64;
    for (int sbi = 0; sbi < nsub; ++sbi) {
        const int sb = pstart + sbi * 64;
        __syncthreads();
        if (t < 64) x2s[t] = (sb + t < pend) ? x2g[sb + t] : INFINITY;
        f32x4 acc[4][4];
#pragma unroll
        for (int i = 0; i < 4; ++i)
#pragma unroll
            for (int j = 0; j < 4; ++j) acc[i][j] = (f32x4)0.f;
        for (int k0i = 0; k0i < NK; ++k0i) {
            const int k0 = k0i * 32;
            __syncthreads();
            {
                int prow = sb + wave * 16 + col;
                if (prow >= pend) prow = pend - 1;
                const float4* src = (const float4*)(X + (size_t)prow * D + k0 + quad * 8);
                float4 a = src[0], b = src[1];
                u32 p0 = (u32)f2bf(a.x) | ((u32)f2bf(a.y) << 16);
                u32 p1 = (u32)f2bf(a.z) | ((u32)f2bf(a.w) << 16);
                u32 p2 = (u32)f2bf(b.x) | ((u32)f2bf(b.y) << 16);
                u32 p3 = (u32)f2bf(b.z) | ((u32)f2bf(b.w) << 16);
                *(uint4*)(Afr + wave * 512 + lane * 8) = make_uint4(p0, p1, p2, p3);
            }
#pragma unroll
            for (int j = 0; j < 4; ++j) {
                int qgrp = qb * 16 + wave * 4 + j;
                gld_lds16(Qbf + ((size_t)qgrp * NK + k0i) * 512 + lane * 8,
                          (void*)(Bfr + (wave * 4 + j) * 512));
            }
            __syncthreads();
            short8 af[4], bqf[4];
#pragma unroll
            for (int i = 0; i < 4; ++i) af[i] = *(const short8*)(Afr + i * 512 + lane * 8);
#pragma unroll
            for (int j = 0; j < 4; ++j) bqf[j] = *(const short8*)(Bfr + (wave * 4 + j) * 512 + lane * 8);
#pragma unroll
            for (int i = 0; i < 4; ++i)
#pragma unroll
                for (int j = 0; j < 4; ++j)
                    acc[i][j] = __builtin_amdgcn_mfma_f32_16x16x32_bf16(af[i], bqf[j], acc[i][j], 0, 0, 0);
        }
#pragma unroll
        for (int i = 0; i < 4; ++i) {
            int pb = 16 * i + quad * 4;
#pragma unroll
            for (int j = 0; j < 4; ++j)
#pragma unroll
                for (int r = 0; r < 4; ++r)
                    ins5(ss[j], si[j], 2.f * acc[i][j][r] - x2s[pb + r], sb + pb + r);
        }
    }
#pragma unroll
    for (int j = 0; j < 4; ++j) { merge_xor(ss[j], si[j], 16); merge_xor(ss[j], si[j], 32); }
    if (quad == 0) {
#pragma unroll
        for (int j = 0; j < 4; ++j) {
            int qg = qb * 256 + wave * 64 + j * 16 + col;
            size_t base = ((size_t)qg * 128 + part) * KTOP;
#pragma unroll
            for (int k = 0; k < KTOP; ++k) { cand_s[base + k] = ss[j][k]; cand_i[base + k] = si[j][k]; }
        }
    }
}

// ---- finalize: pool npart*5 cands -> approx top-16 -> exact rescore -> vote
__launch_bounds__(256)
__global__ void finalize(const float* __restrict__ Q, const float* __restrict__ X,
                         const float* __restrict__ x2g, const int* __restrict__ Y,
                         const float* __restrict__ cand_s, const int* __restrict__ cand_i,
                         float* __restrict__ out, int npart) {
    __shared__ float scs[4][96];
    __shared__ int   sis[4][96];
    const int t = threadIdx.x, lane = t & 63, w = t >> 6;
    const int q = blockIdx.x * 4 + w;
    const int perlane = npart * KTOP / 16;

    if (lane < 16) {
        float ls[KTOP]; int li[KTOP];
#pragma unroll
        for (int k = 0; k < KTOP; ++k) { ls[k] = -INFINITY; li[k] = 0x7fffffff; }
        const float* cs = cand_s + (size_t)q * npart * KTOP + lane * perlane;
        const int*   ci = cand_i + (size_t)q * npart * KTOP + lane * perlane;
        for (int c = 0; c < perlane; ++c) {
            float s = cs[c]; int p = ci[c];
            if (s > ls[KTOP - 1] || (s == ls[KTOP - 1] && p < li[KTOP - 1])) {
                ls[KTOP - 1] = s; li[KTOP - 1] = p;
#pragma unroll
                for (int k = KTOP - 1; k > 0; --k) {
                    bool up = (ls[k] > ls[k - 1]) || (ls[k] == ls[k - 1] && li[k] < li[k - 1]);
                    if (up) {
                        float tf = ls[k]; ls[k] = ls[k - 1]; ls[k - 1] = tf;
                        int   tg = li[k]; li[k] = li[k - 1]; li[k - 1] = tg;
                    }
                }
            }
        }
#pragma unroll
        for (int k = 0; k < KTOP; ++k) { scs[w][lane * KTOP + k] = ls[k]; sis[w][lane * KTOP + k] = li[k]; }
    }
    __syncthreads();
    if (lane == 0) {
        float bs[16]; int bx[16];
#pragma unroll
        for (int m = 0; m < 16; ++m) { bs[m] = -INFINITY; bx[m] = 0x7fffffff; }
        for (int c = 0; c < 80; ++c) {
            float s = scs[w][c]; int p = sis[w][c];
            if (s > bs[15] || (s == bs[15] && p < bx[15])) {
                bs[15] = s; bx[15] = p;
#pragma unroll
                for (int m = 15; m > 0; --m) {
                    bool up = (bs[m] > bs[m - 1]) || (bs[m] == bs[m - 1] && bx[m] < bx[m - 1]);
                    if (up) {
                        float tf = bs[m]; bs[m] = bs[m - 1]; bs[m - 1] = tf;
                        int   tg = bx[m]; bx[m] = bx[m - 1]; bx[m - 1] = tg;
                    }
                }
            }
        }
#pragma unroll
        for (int m = 0; m < 16; ++m) sis[w][80 + m] = bx[m];
    }
    __syncthreads();
    const int c = lane & 15, seg = lane >> 4;
    int idx = sis[w][80 + c];
    const float4* xr = (const float4*)(X + (size_t)idx * D);
    const float4* qr = (const float4*)(Q + (size_t)q * D);
    float d = 0.f;
    for (int u = seg * 32; u < seg * 32 + 32; ++u) {
        float4 a = qr[u], b = xr[u];
        d = fmaf(a.x, b.x, d); d = fmaf(a.y, b.y, d);
        d = fmaf(a.z, b.z, d); d = fmaf(a.w, b.w, d);
    }
    d += __shfl_xor(d, 16);
    d += __shfl_xor(d, 32);
    float sc = 2.f * d - x2g[idx];
    if (seg == 0) scs[w][80 + c] = sc;
    __syncthreads();
    if (lane == 0) {
        float bs[KTOP]; int bx[KTOP];
#pragma unroll
        for (int k = 0; k < KTOP; ++k) { bs[k] = -INFINITY; bx[k] = 0x7fffffff; }
        for (int c2 = 0; c2 < 16; ++c2) {
            float s = scs[w][80 + c2]; int p = sis[w][80 + c2];
            if (s > bs[KTOP - 1] || (s == bs[KTOP - 1] && p < bx[KTOP - 1])) {
                bs[KTOP - 1] = s; bx[KTOP - 1] = p;
#pragma unroll
                for (int k = KTOP - 1; k > 0; --k) {
                    bool up = (bs[k] > bs[k - 1]) || (bs[k] == bs[k - 1] && bx[k] < bx[k - 1]);
                    if (up) {
                        float tf = bs[k]; bs[k] = bs[k - 1]; bs[k - 1] = tf;
                        int   tg = bx[k]; bx[k] = bx[k - 1]; bx[k - 1] = tg;
                    }
                }
            }
        }
        float sum = 0.f;
#pragma unroll
        for (int k = 0; k < KTOP; ++k) sum += (float)Y[bx[k]];
        out[2 * q]     = sum * 0.2f;
        out[2 * q + 1] = 0.f;
    }
}

extern "C" void kernel_launch(void* const* d_in, const int* in_sizes, int n_in,
                              void* d_out, int out_size, void* d_ws, size_t ws_size,
                              hipStream_t stream) {
    const float* Qf = (const float*)d_in[0];
    const float* Xf = (const float*)d_in[1];
    const int*   Y  = (const int*)d_in[2];
    float* out = (float*)d_out;
    char* ws = (char*)d_ws;

    constexpr size_t XBF_B  = (size_t)NPTS_PAD * D * 2;       // 103,809,024
    constexpr size_t QBF_B  = 2097152;
    constexpr size_t X2_B   = (size_t)NPTS_PAD * 4;           //     405,504
    constexpr size_t CAND_B = (size_t)B * NPART * KTOP * 4;   //   1,966,080
    constexpr size_t NEED   = XBF_B + QBF_B + X2_B + 2 * CAND_B;

    if (ws_size >= NEED) {
        u16*   Xbf    = (u16*)ws;
        u16*   Qbf    = (u16*)(ws + XBF_B);
        float* x2     = (float*)(ws + XBF_B + QBF_B);
        float* cand_s = (float*)(ws + XBF_B + QBF_B + X2_B);
        int*   cand_i = (int*)  (ws + XBF_B + QBF_B + X2_B + CAND_B);
        hipLaunchKernelGGL(prep_q32, dim3(512),       dim3(256), 0, stream, Qf, Qbf);
        hipLaunchKernelGGL(prep_x2,  dim3(NPG32),     dim3(256), 0, stream, Xf, Xbf, x2);
        hipLaunchKernelGGL(knn_qreg, dim3(NPART, 16), dim3(256), 0, stream, Xbf, Qbf, x2, cand_s, cand_i);
        hipLaunchKernelGGL(finalize, dim3(B / 4),     dim3(256), 0, stream, Qf, Xf, x2, Y, cand_s, cand_i, out, NPART);
    } else {                                   // round-2/3 proven fallback (~13 MB)
        u16*   Qbf    = (u16*)ws;
        float* x2     = (float*)(ws + 2097152);
        float* cand_s = (float*)(ws + 2497152);
        int*   cand_i = (int*)  (ws + 7740032);
        hipLaunchKernelGGL(prep_q16,  dim3(512),      dim3(256), 0, stream, Qf, Qbf);
        hipLaunchKernelGGL(x2_kernel, dim3(N / 4),    dim3(256), 0, stream, Xf, x2, N);
        hipLaunchKernelGGL(knn_conv,  dim3(8, 128),   dim3(256), 0, stream, Xf, Qbf, x2, cand_s, cand_i);
        hipLaunchKernelGGL(finalize,  dim3(B / 4),    dim3(256), 0, stream, Qf, Xf, x2, Y, cand_s, cand_i, out, 128);
    }
}

// Round 5
// 655.248 us; speedup vs baseline: 1.0491x; 1.0491x over previous
//
#include <hip/hip_runtime.h>
#include <math.h>

typedef unsigned int   u32;
typedef unsigned short u16;
typedef short short8 __attribute__((ext_vector_type(8)));   // 8 bf16 = 4 VGPRs
typedef float f32x4   __attribute__((ext_vector_type(4)));
typedef float f32x16  __attribute__((ext_vector_type(16)));

constexpr int B    = 2048;
constexpr int D    = 512;
constexpr int N    = 100000;
constexpr int KTOP = 5;
constexpr int NK   = 16;                  // 512 / 32 (fallback path)

// Big path: 32x32x16 MFMA. 32-point groups (pg32) are the N-tile unit.
constexpr int NPART    = 48;
constexpr int CHUNK    = 2112;            // 66 pg32 of 32; 48*2112 = 101376 >= N
constexpr int ITERS    = CHUNK / 32;      // 66
constexpr int NPTS_PAD = NPART * CHUNK;   // 101376
constexpr int NPG32    = NPTS_PAD / 32;   // 3168

__device__ __forceinline__ u16 f2bf(float f) {   // RNE, finite normals
    u32 u = __float_as_uint(f);
    return (u16)((u + 0x7fffu + ((u >> 16) & 1u)) >> 16);
}

__device__ __forceinline__ void gld_lds16(const void* g, void* l) {
    __builtin_amdgcn_global_load_lds((const __attribute__((address_space(1))) u32*)g,
                                     (__attribute__((address_space(3))) u32*)l, 16, 0, 0);
}

__device__ __forceinline__ void ins5(float (&s)[KTOP], int (&x)[KTOP], float v, int p) {
    if (v > s[KTOP - 1]) {                 // strict >: earlier (lower) idx wins ties
        s[KTOP - 1] = v; x[KTOP - 1] = p;
#pragma unroll
        for (int k = KTOP - 1; k > 0; --k) {
            if (s[k] > s[k - 1]) {
                float tf = s[k]; s[k] = s[k - 1]; s[k - 1] = tf;
                int   tg = x[k]; x[k] = x[k - 1]; x[k - 1] = tg;
            }
        }
    }
}

__device__ __forceinline__ void merge_xor(float (&s)[KTOP], int (&x)[KTOP], int mask) {
    float bs[KTOP], as[KTOP]; int bx[KTOP], ax[KTOP];
#pragma unroll
    for (int k = 0; k < KTOP; ++k) {
        bs[k] = __shfl_xor(s[k], mask); bx[k] = __shfl_xor(x[k], mask);
        as[k] = s[k]; ax[k] = x[k];
    }
#pragma unroll
    for (int k = 0; k < KTOP; ++k) {
        bool ta = (as[0] > bs[0]) || ((as[0] == bs[0]) && (ax[0] < bx[0]));
        s[k] = ta ? as[0] : bs[0];
        x[k] = ta ? ax[0] : bx[0];
#pragma unroll
        for (int m = 0; m < KTOP - 1; ++m) {
            as[m] = ta ? as[m + 1] : as[m];     ax[m] = ta ? ax[m + 1] : ax[m];
            bs[m] = ta ? bs[m]     : bs[m + 1]; bx[m] = ta ? bx[m]     : bx[m + 1];
        }
        as[KTOP - 1] = ta ? -INFINITY : as[KTOP - 1];
        bs[KTOP - 1] = ta ? bs[KTOP - 1] : -INFINITY;
    }
}

// ---- Q -> bf16 B-frags for 32x32x16: lane = (q&31) + 32*octet, k contiguous 8
__global__ void prep_q32(const float* __restrict__ Q, u16* __restrict__ Qbf) {
    int tid  = blockIdx.x * 256 + threadIdx.x;     // 131072 = 2048*64
    int q    = tid >> 6;
    int koct = tid & 63;                           // k = koct*8 .. +7
    const float4* src = (const float4*)(Q + (size_t)q * D + koct * 8);
    float4 a = src[0], b = src[1];
    u32 p0 = (u32)f2bf(a.x) | ((u32)f2bf(a.y) << 16);
    u32 p1 = (u32)f2bf(a.z) | ((u32)f2bf(a.w) << 16);
    u32 p2 = (u32)f2bf(b.x) | ((u32)f2bf(b.y) << 16);
    u32 p3 = (u32)f2bf(b.z) | ((u32)f2bf(b.w) << 16);
    int kstep = koct >> 1, octet = koct & 1;
    int lane  = (q & 31) + 32 * octet;
    size_t frag = (size_t)(q >> 5) * 32 + kstep;
    *(uint4*)(Qbf + (frag * 64 + lane) * 8) = make_uint4(p0, p1, p2, p3);
}

// ---- Q -> bf16 in 16x16x32 B-frag order (fallback path) -------------------
__global__ void prep_q16(const float* __restrict__ Q, u16* __restrict__ Qbf) {
    int tid  = blockIdx.x * 256 + threadIdx.x;     // 131072
    int q    = tid >> 6;
    int koct = tid & 63;
    const float4* src = (const float4*)(Q + (size_t)q * D + koct * 8);
    float4 a = src[0], b = src[1];
    u32 p0 = (u32)f2bf(a.x) | ((u32)f2bf(a.y) << 16);
    u32 p1 = (u32)f2bf(a.z) | ((u32)f2bf(a.w) << 16);
    u32 p2 = (u32)f2bf(b.x) | ((u32)f2bf(b.y) << 16);
    u32 p3 = (u32)f2bf(b.z) | ((u32)f2bf(b.w) << 16);
    int frag = (q >> 4) * NK + (koct >> 2);
    int lane = (q & 15) + 16 * (koct & 3);
    *(uint4*)(Qbf + (size_t)frag * 512 + lane * 8) = make_uint4(p0, p1, p2, p3);
}

// ---- X -> bf16 A-frags, COALESCED: wave reads whole 2KB rows, transposes
// through a padded LDS tile ([32][520] u16; +8 pad -> 4-way read conflict max),
// shfl-reduces x2, writes frags coalesced. Replaces the 32B-per-lane scattered
// read pattern (suspected ~200-300us of the constant ~370us non-knn gap).
__global__ void prep_x2(const float* __restrict__ X, u16* __restrict__ Xbf,
                        float* __restrict__ x2) {
    __shared__ __attribute__((aligned(16))) u16 Xl[32][520];
    const int t = threadIdx.x, lane = t & 63, wave = t >> 6;
    const int pg = blockIdx.x;                    // 0..NPG32-1
#pragma unroll
    for (int i = 0; i < 8; ++i) {
        const int p     = wave * 8 + i;           // 0..31 within pg
        const int point = pg * 32 + p;
        float4 a = make_float4(0.f, 0.f, 0.f, 0.f), b = a;
        if (point < N) {
            const float4* src = (const float4*)(X + (size_t)point * D + lane * 8);
            a = src[0]; b = src[1];
        }
        float s = 0.f;
        s = fmaf(a.x, a.x, s); s = fmaf(a.y, a.y, s);
        s = fmaf(a.z, a.z, s); s = fmaf(a.w, a.w, s);
        s = fmaf(b.x, b.x, s); s = fmaf(b.y, b.y, s);
        s = fmaf(b.z, b.z, s); s = fmaf(b.w, b.w, s);
        u32 p0 = (u32)f2bf(a.x) | ((u32)f2bf(a.y) << 16);
        u32 p1 = (u32)f2bf(a.z) | ((u32)f2bf(a.w) << 16);
        u32 p2 = (u32)f2bf(b.x) | ((u32)f2bf(b.y) << 16);
        u32 p3 = (u32)f2bf(b.z) | ((u32)f2bf(b.w) << 16);
        *(uint4*)&Xl[p][lane * 8] = make_uint4(p0, p1, p2, p3);
        s += __shfl_xor(s, 1);  s += __shfl_xor(s, 2);  s += __shfl_xor(s, 4);
        s += __shfl_xor(s, 8);  s += __shfl_xor(s, 16); s += __shfl_xor(s, 32);
        if (lane == 0) x2[pg * 32 + p] = (point < N) ? s : INFINITY;
    }
    __syncthreads();
    // out frag (pg*32+ks)*64 + l holds X[pg*32+(l&31)][ks*16+(l>>5)*8 ..+7]
#pragma unroll
    for (int v = 0; v < 8; ++v) {
        const int ks = v * 4 + wave;              // 0..31
        uint4 o = *(const uint4*)&Xl[lane & 31][ks * 16 + (lane >> 5) * 8];
        *(uint4*)(Xbf + (((size_t)pg * 32 + ks) * 64 + lane) * 8) = o;
    }
}

// ---- x2 (fallback path only) ----------------------------------------------
__global__ void x2_kernel(const float* __restrict__ X, float* __restrict__ x2, int total) {
    int lane = threadIdx.x & 63;
    int wid  = (int)((blockIdx.x * blockDim.x + threadIdx.x) >> 6);
    if (wid >= total) return;
    if (wid >= N) { if (lane == 0) x2[wid] = INFINITY; return; }
    const float* row = X + (size_t)wid * D;
    float s = 0.f;
    for (int c = lane; c < D; c += 64) { float v = row[c]; s = fmaf(v, v, s); }
#pragma unroll
    for (int off = 32; off > 0; off >>= 1) s += __shfl_down(s, off);
    if (lane == 0) x2[wid] = s;
}

// ---- main: 32x32x16, counted-vmcnt 4-deep pipeline (T3/T4). 4 ring buffers
// of 8 ksteps (8KB each); per 8-MFMA phase: s_waitcnt vmcnt(4); s_barrier;
// issue phase+3. Prefetch distance = 3 phases (~600+cyc, covers L3 latency);
// vmcnt never drains to 0 in the main loop (round-4 __syncthreads drained
// fresh loads at every barrier -> latency-bound at ~7% matrix-pipe busy).
// x2 preloaded to LDS so staging gld_lds are the ONLY in-loop vmem ops.
__launch_bounds__(256, 3)
__global__ void knn_qreg(const u16* __restrict__ Xbf, const u16* __restrict__ Qbf,
                         const float* __restrict__ x2g,
                         float* __restrict__ cand_s, int* __restrict__ cand_i) {
    __shared__ __attribute__((aligned(16))) u16 Afr[4][8 * 512];   // 4 x 8KB ring
    __shared__ __attribute__((aligned(16))) float x2s[CHUNK];      // 8.25 KB
    const int t    = threadIdx.x;
    const int lane = t & 63;
    const int wave = t >> 6;              // 0..3
    const int hid  = lane >> 5;           // k-octet / C-row +4 selector
    const int col  = lane & 31;           // query within group
    const int part = blockIdx.x;          // 0..47  (48 == 0 mod 8: all 16 qb of
    const int qb   = blockIdx.y;          // 0..15   a part land on one XCD)
    const int pg0    = part * ITERS;
    const int pstart = part * CHUNK;

    // Resident Q: 32 queries x 32 ksteps; B-frag lane holds col, k-octet hid
    const int qg = qb * 4 + wave;         // 0..63
    short8 bq[32];
#pragma unroll
    for (int ks = 0; ks < 32; ++ks)
        bq[ks] = *(const short8*)(Qbf + (((size_t)qg * 32 + ks) * 64 + lane) * 8);
    // Pin bq in registers: memory clobber forbids re-loading from Qbf in-loop.
    asm volatile("" ::: "memory");

    // x2 chunk -> LDS once (keeps the main loop free of non-staging vmem).
    for (int i = t; i < CHUNK / 4; i += 256)
        ((float4*)x2s)[i] = ((const float4*)(x2g + pstart))[i];

    float ss[KTOP]; int si[KTOP];
#pragma unroll
    for (int k = 0; k < KTOP; ++k) { ss[k] = -INFINITY; si[k] = 0x7fffffff; }

    // Stage phase ph (8 ksteps = 8KB) into ring buffer ph%4; wave w stages
    // frags w*2, w*2+1. Dst is wave-uniform base + lane*16 (gld_lds req).
    auto issue = [&](int ph) {
        const int buf = ph & 3;
        const size_t fb = ((size_t)(pg0 + (ph >> 2)) * 32 + (ph & 3) * 8 + wave * 2) * 64;
        const u16* src = Xbf + (fb + lane) * 8;
        u16* dst = &Afr[buf][(wave * 2) * 512 + lane * 8];
        gld_lds16(src, dst);
        gld_lds16(src + 512, dst + 512);
    };

    auto epi = [&](const f32x16& acc, int it) {
        // C layout: col=lane&31 (query), row=(reg&3)+8*(reg>>2)+4*hid (point)
        const int base = it * 32 + hid * 4;
        float4 xx0 = *(const float4*)&x2s[base];
        float4 xx1 = *(const float4*)&x2s[base + 8];
        float4 xx2 = *(const float4*)&x2s[base + 16];
        float4 xx3 = *(const float4*)&x2s[base + 24];
        const int PA = pstart + base;
        float s0  = fmaf(2.f, acc[0],  -xx0.x), s1  = fmaf(2.f, acc[1],  -xx0.y);
        float s2  = fmaf(2.f, acc[2],  -xx0.z), s3  = fmaf(2.f, acc[3],  -xx0.w);
        float s4  = fmaf(2.f, acc[4],  -xx1.x), s5  = fmaf(2.f, acc[5],  -xx1.y);
        float s6  = fmaf(2.f, acc[6],  -xx1.z), s7  = fmaf(2.f, acc[7],  -xx1.w);
        float s8  = fmaf(2.f, acc[8],  -xx2.x), s9  = fmaf(2.f, acc[9],  -xx2.y);
        float s10 = fmaf(2.f, acc[10], -xx2.z), s11 = fmaf(2.f, acc[11], -xx2.w);
        float s12 = fmaf(2.f, acc[12], -xx3.x), s13 = fmaf(2.f, acc[13], -xx3.y);
        float s14 = fmaf(2.f, acc[14], -xx3.z), s15 = fmaf(2.f, acc[15], -xx3.w);
        float m0 = fmaxf(fmaxf(s0, s1),   fmaxf(s2, s3));
        float m1 = fmaxf(fmaxf(s4, s5),   fmaxf(s6, s7));
        float m2 = fmaxf(fmaxf(s8, s9),   fmaxf(s10, s11));
        float m3 = fmaxf(fmaxf(s12, s13), fmaxf(s14, s15));
        float mx = fmaxf(fmaxf(m0, m1), fmaxf(m2, m3));
        if (mx > ss[KTOP - 1]) {
            ins5(ss, si, s0,  PA + 0);  ins5(ss, si, s1,  PA + 1);
            ins5(ss, si, s2,  PA + 2);  ins5(ss, si, s3,  PA + 3);
            ins5(ss, si, s4,  PA + 8);  ins5(ss, si, s5,  PA + 9);
            ins5(ss, si, s6,  PA + 10); ins5(ss, si, s7,  PA + 11);
            ins5(ss, si, s8,  PA + 16); ins5(ss, si, s9,  PA + 17);
            ins5(ss, si, s10, PA + 18); ins5(ss, si, s11, PA + 19);
            ins5(ss, si, s12, PA + 24); ins5(ss, si, s13, PA + 25);
            ins5(ss, si, s14, PA + 26); ins5(ss, si, s15, PA + 27);
        }
    };

#define WBAR(NSTR) asm volatile("s_waitcnt vmcnt(" NSTR ")\n\ts_barrier" ::: "memory")

    __syncthreads();                       // x2s visible; drains x2s loads (vmcnt clean)
    issue(0); issue(1); issue(2);          // 6 loads in flight per wave

    for (int it = 0; it < ITERS - 1; ++it) {
        f32x16 acc = (f32x16)0.f;
#pragma unroll
        for (int sub = 0; sub < 4; ++sub) {
            WBAR("4");                     // phase loads done; 4 (2 phases) in flight
            issue(it * 4 + sub + 3);       // writes buf read 1 phase ago (barrier-safe)
#pragma unroll
            for (int k = 0; k < 8; ++k) {
                short8 af = *(const short8*)&Afr[sub][k * 512 + lane * 8];
                acc = __builtin_amdgcn_mfma_f32_32x32x16_bf16(af, bq[sub * 8 + k], acc, 0, 0, 0);
            }
        }
        epi(acc, it);
    }
    {   // peeled last iteration: drain 4 -> 4 -> 2 -> 0
        const int it = ITERS - 1;
        f32x16 acc = (f32x16)0.f;
        WBAR("4");
        issue(it * 4 + 3);                 // final phase (NPH-1)
#pragma unroll
        for (int k = 0; k < 8; ++k) {
            short8 af = *(const short8*)&Afr[0][k * 512 + lane * 8];
            acc = __builtin_amdgcn_mfma_f32_32x32x16_bf16(af, bq[k], acc, 0, 0, 0);
        }
        WBAR("4");
#pragma unroll
        for (int k = 0; k < 8; ++k) {
            short8 af = *(const short8*)&Afr[1][k * 512 + lane * 8];
            acc = __builtin_amdgcn_mfma_f32_32x32x16_bf16(af, bq[8 + k], acc, 0, 0, 0);
        }
        WBAR("2");
#pragma unroll
        for (int k = 0; k < 8; ++k) {
            short8 af = *(const short8*)&Afr[2][k * 512 + lane * 8];
            acc = __builtin_amdgcn_mfma_f32_32x32x16_bf16(af, bq[16 + k], acc, 0, 0, 0);
        }
        WBAR("0");
#pragma unroll
        for (int k = 0; k < 8; ++k) {
            short8 af = *(const short8*)&Afr[3][k * 512 + lane * 8];
            acc = __builtin_amdgcn_mfma_f32_32x32x16_bf16(af, bq[24 + k], acc, 0, 0, 0);
        }
        epi(acc, it);
    }
#undef WBAR

    merge_xor(ss, si, 32);                // lanes l, l^32 hold the same query
    if (hid == 0) {
        int q = qg * 32 + col;
        size_t base = ((size_t)q * NPART + part) * KTOP;
#pragma unroll
        for (int k = 0; k < KTOP; ++k) { cand_s[base + k] = ss[k]; cand_i[base + k] = si[k]; }
    }
}

// ---- fallback main (round-2/3 proven path, in-loop conversion) ------------
__launch_bounds__(256)
__global__ void knn_conv(const float* __restrict__ X, const u16* __restrict__ Qbf,
                         const float* __restrict__ x2g,
                         float* __restrict__ cand_s, int* __restrict__ cand_i) {
    __shared__ __attribute__((aligned(16))) u16 Bfr[16 * 512];
    __shared__ __attribute__((aligned(16))) u16 Afr[4 * 512];
    __shared__ float x2s[64];
    const int t = threadIdx.x, lane = t & 63, wave = t >> 6;
    const int quad = lane >> 4, col = lane & 15;
    const int qb = blockIdx.x, part = blockIdx.y;
    const int pstart = part * 782;
    const int pend   = min(pstart + 782, N);

    float ss[4][KTOP]; int si[4][KTOP];
#pragma unroll
    for (int j = 0; j < 4; ++j)
#pragma unroll
        for (int k = 0; k < KTOP; ++k) { ss[j][k] = -INFINITY; si[j][k] = 0x7fffffff; }

    const int nsub = (pend - pstart + 63) / 64;
    for (int sbi = 0; sbi < nsub; ++sbi) {
        const int sb = pstart + sbi * 64;
        __syncthreads();
        if (t < 64) x2s[t] = (sb + t < pend) ? x2g[sb + t] : INFINITY;
        f32x4 acc[4][4];
#pragma unroll
        for (int i = 0; i < 4; ++i)
#pragma unroll
            for (int j = 0; j < 4; ++j) acc[i][j] = (f32x4)0.f;
        for (int k0i = 0; k0i < NK; ++k0i) {
            const int k0 = k0i * 32;
            __syncthreads();
            {
                int prow = sb + wave * 16 + col;
                if (prow >= pend) prow = pend - 1;
                const float4* src = (const float4*)(X + (size_t)prow * D + k0 + quad * 8);
                float4 a = src[0], b = src[1];
                u32 p0 = (u32)f2bf(a.x) | ((u32)f2bf(a.y) << 16);
                u32 p1 = (u32)f2bf(a.z) | ((u32)f2bf(a.w) << 16);
                u32 p2 = (u32)f2bf(b.x) | ((u32)f2bf(b.y) << 16);
                u32 p3 = (u32)f2bf(b.z) | ((u32)f2bf(b.w) << 16);
                *(uint4*)(Afr + wave * 512 + lane * 8) = make_uint4(p0, p1, p2, p3);
            }
#pragma unroll
            for (int j = 0; j < 4; ++j) {
                int qgrp = qb * 16 + wave * 4 + j;
                gld_lds16(Qbf + ((size_t)qgrp * NK + k0i) * 512 + lane * 8,
                          (void*)(Bfr + (wave * 4 + j) * 512));
            }
            __syncthreads();
            short8 af[4], bqf[4];
#pragma unroll
            for (int i = 0; i < 4; ++i) af[i] = *(const short8*)(Afr + i * 512 + lane * 8);
#pragma unroll
            for (int j = 0; j < 4; ++j) bqf[j] = *(const short8*)(Bfr + (wave * 4 + j) * 512 + lane * 8);
#pragma unroll
            for (int i = 0; i < 4; ++i)
#pragma unroll
                for (int j = 0; j < 4; ++j)
                    acc[i][j] = __builtin_amdgcn_mfma_f32_16x16x32_bf16(af[i], bqf[j], acc[i][j], 0, 0, 0);
        }
#pragma unroll
        for (int i = 0; i < 4; ++i) {
            int pb = 16 * i + quad * 4;
#pragma unroll
            for (int j = 0; j < 4; ++j)
#pragma unroll
                for (int r = 0; r < 4; ++r)
                    ins5(ss[j], si[j], 2.f * acc[i][j][r] - x2s[pb + r], sb + pb + r);
        }
    }
#pragma unroll
    for (int j = 0; j < 4; ++j) { merge_xor(ss[j], si[j], 16); merge_xor(ss[j], si[j], 32); }
    if (quad == 0) {
#pragma unroll
        for (int j = 0; j < 4; ++j) {
            int qg = qb * 256 + wave * 64 + j * 16 + col;
            size_t base = ((size_t)qg * 128 + part) * KTOP;
#pragma unroll
            for (int k = 0; k < KTOP; ++k) { cand_s[base + k] = ss[j][k]; cand_i[base + k] = si[j][k]; }
        }
    }
}

// ---- finalize: pool npart*5 cands -> approx top-16 -> exact rescore -> vote
__launch_bounds__(256)
__global__ void finalize(const float* __restrict__ Q, const float* __restrict__ X,
                         const float* __restrict__ x2g, const int* __restrict__ Y,
                         const float* __restrict__ cand_s, const int* __restrict__ cand_i,
                         float* __restrict__ out, int npart) {
    __shared__ float scs[4][96];
    __shared__ int   sis[4][96];
    const int t = threadIdx.x, lane = t & 63, w = t >> 6;
    const int q = blockIdx.x * 4 + w;
    const int perlane = npart * KTOP / 16;

    if (lane < 16) {
        float ls[KTOP]; int li[KTOP];
#pragma unroll
        for (int k = 0; k < KTOP; ++k) { ls[k] = -INFINITY; li[k] = 0x7fffffff; }
        const float* cs = cand_s + (size_t)q * npart * KTOP + lane * perlane;
        const int*   ci = cand_i + (size_t)q * npart * KTOP + lane * perlane;
        for (int c = 0; c < perlane; ++c) {
            float s = cs[c]; int p = ci[c];
            if (s > ls[KTOP - 1] || (s == ls[KTOP - 1] && p < li[KTOP - 1])) {
                ls[KTOP - 1] = s; li[KTOP - 1] = p;
#pragma unroll
                for (int k = KTOP - 1; k > 0; --k) {
                    bool up = (ls[k] > ls[k - 1]) || (ls[k] == ls[k - 1] && li[k] < li[k - 1]);
                    if (up) {
                        float tf = ls[k]; ls[k] = ls[k - 1]; ls[k - 1] = tf;
                        int   tg = li[k]; li[k] = li[k - 1]; li[k - 1] = tg;
                    }
                }
            }
        }
#pragma unroll
        for (int k = 0; k < KTOP; ++k) { scs[w][lane * KTOP + k] = ls[k]; sis[w][lane * KTOP + k] = li[k]; }
    }
    __syncthreads();
    if (lane == 0) {
        float bs[16]; int bx[16];
#pragma unroll
        for (int m = 0; m < 16; ++m) { bs[m] = -INFINITY; bx[m] = 0x7fffffff; }
        for (int c = 0; c < 80; ++c) {
            float s = scs[w][c]; int p = sis[w][c];
            if (s > bs[15] || (s == bs[15] && p < bx[15])) {
                bs[15] = s; bx[15] = p;
#pragma unroll
                for (int m = 15; m > 0; --m) {
                    bool up = (bs[m] > bs[m - 1]) || (bs[m] == bs[m - 1] && bx[m] < bx[m - 1]);
                    if (up) {
                        float tf = bs[m]; bs[m] = bs[m - 1]; bs[m - 1] = tf;
                        int   tg = bx[m]; bx[m] = bx[m - 1]; bx[m - 1] = tg;
                    }
                }
            }
        }
#pragma unroll
        for (int m = 0; m < 16; ++m) sis[w][80 + m] = bx[m];
    }
    __syncthreads();
    const int c = lane & 15, seg = lane >> 4;
    int idx = sis[w][80 + c];
    const float4* xr = (const float4*)(X + (size_t)idx * D);
    const float4* qr = (const float4*)(Q + (size_t)q * D);
    float d = 0.f;
    for (int u = seg * 32; u < seg * 32 + 32; ++u) {
        float4 a = qr[u], b = xr[u];
        d = fmaf(a.x, b.x, d); d = fmaf(a.y, b.y, d);
        d = fmaf(a.z, b.z, d); d = fmaf(a.w, b.w, d);
    }
    d += __shfl_xor(d, 16);
    d += __shfl_xor(d, 32);
    float sc = 2.f * d - x2g[idx];
    if (seg == 0) scs[w][80 + c] = sc;
    __syncthreads();
    if (lane == 0) {
        float bs[KTOP]; int bx[KTOP];
#pragma unroll
        for (int k = 0; k < KTOP; ++k) { bs[k] = -INFINITY; bx[k] = 0x7fffffff; }
        for (int c2 = 0; c2 < 16; ++c2) {
            float s = scs[w][80 + c2]; int p = sis[w][80 + c2];
            if (s > bs[KTOP - 1] || (s == bs[KTOP - 1] && p < bx[KTOP - 1])) {
                bs[KTOP - 1] = s; bx[KTOP - 1] = p;
#pragma unroll
                for (int k = KTOP - 1; k > 0; --k) {
                    bool up = (bs[k] > bs[k - 1]) || (bs[k] == bs[k - 1] && bx[k] < bx[k - 1]);
                    if (up) {
                        float tf = bs[k]; bs[k] = bs[k - 1]; bs[k - 1] = tf;
                        int   tg = bx[k]; bx[k] = bx[k - 1]; bx[k - 1] = tg;
                    }
                }
            }
        }
        float sum = 0.f;
#pragma unroll
        for (int k = 0; k < KTOP; ++k) sum += (float)Y[bx[k]];
        out[2 * q]     = sum * 0.2f;
        out[2 * q + 1] = 0.f;
    }
}

extern "C" void kernel_launch(void* const* d_in, const int* in_sizes, int n_in,
                              void* d_out, int out_size, void* d_ws, size_t ws_size,
                              hipStream_t stream) {
    const float* Qf = (const float*)d_in[0];
    const float* Xf = (const float*)d_in[1];
    const int*   Y  = (const int*)d_in[2];
    float* out = (float*)d_out;
    char* ws = (char*)d_ws;

    constexpr size_t XBF_B  = (size_t)NPTS_PAD * D * 2;       // 103,809,024
    constexpr size_t QBF_B  = 2097152;
    constexpr size_t X2_B   = (size_t)NPTS_PAD * 4;           //     405,504
    constexpr size_t CAND_B = (size_t)B * NPART * KTOP * 4;   //   1,966,080
    constexpr size_t NEED   = XBF_B + QBF_B + X2_B + 2 * CAND_B;

    if (ws_size >= NEED) {
        u16*   Xbf    = (u16*)ws;
        u16*   Qbf    = (u16*)(ws + XBF_B);
        float* x2     = (float*)(ws + XBF_B + QBF_B);
        float* cand_s = (float*)(ws + XBF_B + QBF_B + X2_B);
        int*   cand_i = (int*)  (ws + XBF_B + QBF_B + X2_B + CAND_B);
        hipLaunchKernelGGL(prep_q32, dim3(512),       dim3(256), 0, stream, Qf, Qbf);
        hipLaunchKernelGGL(prep_x2,  dim3(NPG32),     dim3(256), 0, stream, Xf, Xbf, x2);
        hipLaunchKernelGGL(knn_qreg, dim3(NPART, 16), dim3(256), 0, stream, Xbf, Qbf, x2, cand_s, cand_i);
        hipLaunchKernelGGL(finalize, dim3(B / 4),     dim3(256), 0, stream, Qf, Xf, x2, Y, cand_s, cand_i, out, NPART);
    } else {                                   // round-2/3 proven fallback (~13 MB)
        u16*   Qbf    = (u16*)ws;
        float* x2     = (float*)(ws + 2097152);
        float* cand_s = (float*)(ws + 2497152);
        int*   cand_i = (int*)  (ws + 7740032);
        hipLaunchKernelGGL(prep_q16,  dim3(512),      dim3(256), 0, stream, Qf, Qbf);
        hipLaunchKernelGGL(x2_kernel, dim3(N / 4),    dim3(256), 0, stream, Xf, x2, N);
        hipLaunchKernelGGL(knn_conv,  dim3(8, 128),   dim3(256), 0, stream, Xf, Qbf, x2, cand_s, cand_i);
        hipLaunchKernelGGL(finalize,  dim3(B / 4),    dim3(256), 0, stream, Qf, Xf, x2, Y, cand_s, cand_i, out, 128);
    }
}